// Round 18
// baseline (79.711 us; speedup 1.0000x reference)
//
#include <hip/hip_runtime.h>
#include <hip/hip_bf16.h>

#define B_ 32
#define L_ 512
#define H_ 1024
#define E_ 8
#define R_ 16

typedef float f32x4 __attribute__((ext_vector_type(4)));
typedef __bf16 bf16x8 __attribute__((ext_vector_type(8)));
typedef __bf16 bf16x4 __attribute__((ext_vector_type(4)));

static __device__ __forceinline__ __bf16 f2b(float f) { return (__bf16)f; }

static __device__ __forceinline__ f32x4 MFMA(bf16x8 a, bf16x8 b, f32x4 c) {
  return __builtin_amdgcn_mfma_f32_16x16x32_bf16(a, b, c, 0, 0, 0);
}

// ============ ABLATION 1: tile-ordered pure copy (no LDS, no barrier) ======
// Identical grid/tile/swizzle/row-pattern to the main kernel, but the body is
// a register-only copy. Measures: does TILE-ORDERED access stream at probe
// rate? (probe = grid-stride = 21.9 us for the same bytes)
__global__ __launch_bounds__(512) void tile_copy_kernel(
    const float* __restrict__ x, float* __restrict__ out)
{
  const int t   = threadIdx.x;
  const int bid = blockIdx.x;
  const int tile = (bid & 7) * 128 + (bid >> 3);   // same XCD swizzle
  const int b    = tile >> 5;
  const int l0   = (tile & 31) * 16;

  const int row = t >> 5;                   // 16 rows, 32 threads each
  const int c0  = (t & 31) * 4;
  const float* xr = x   + ((size_t)b * L_ + l0 + row) * H_;
  float*       orow = out + ((size_t)b * L_ + l0 + row) * H_;
#pragma unroll
  for (int i = 0; i < 8; ++i) {
    float4 v = *(const float4*)(xr + c0 + i * 128);
    *(float4*)(orow + c0 + i * 128) = v;
  }
}

// ============ ABLATION 2: stage -> barrier -> epilogue (R14 shell) =========
// Literal R14 staging (f32->bf16->LDS) and literal R14 epilogue, with zero
// compute between. Measures the added cost of the LDS roundtrip + cvt + one
// barrier on top of tile-ordered access.
__global__ __launch_bounds__(512) void shell_kernel(
    const float* __restrict__ x, float* __restrict__ out)
{
  constexpr int XW = 1036;
  __shared__ __bf16 xs[16][XW];

  const int t    = threadIdx.x;
  const int w    = t >> 6;
  const int lane = t & 63;

  const int bid  = blockIdx.x;
  const int tile = (bid & 7) * 128 + (bid >> 3);
  const int b    = tile >> 5;
  const int l0   = (tile & 31) * 16;

  const int row = 2 * w + (lane >> 5);
  const int c0  = (lane & 31) * 4;

  {
    const float* xrr = x + ((size_t)b * L_ + l0 + row) * H_;
#pragma unroll
    for (int i = 0; i < 8; ++i) {
      float4 v = *(const float4*)(xrr + c0 + i * 128);
      bf16x4 bv = { f2b(v.x), f2b(v.y), f2b(v.z), f2b(v.w) };
      *(bf16x4*)&xs[row][c0 + i * 128] = bv;
    }
  }
  __syncthreads();
  {
    float* outrow = out + ((size_t)b * L_ + l0 + row) * H_;
#pragma unroll
    for (int it = 0; it < 8; ++it) {
      const int col = it * 128 + (lane & 31) * 4;
      bf16x4 v = *(const bf16x4*)&xs[row][col];
      float4 o = { (float)v[0], (float)v[1], (float)v[2], (float)v[3] };
      *(float4*)(outrow + col) = o;
    }
  }
}

// ---------------- prep: f32 weights -> bf16 in ws; + gates -----------------
__global__ __launch_bounds__(256) void moe_prep_kernel(
    const float* __restrict__ x, const float* __restrict__ rw,
    const float* __restrict__ ldown, const float* __restrict__ lup,
    __bf16* __restrict__ ldb, __bf16* __restrict__ lub,
    float* __restrict__ gws)
{
  const int bid = blockIdx.x;
  if (bid < 256) {
    const int base = bid * 1024 + threadIdx.x * 4;
    const float* src; __bf16* dst; int off;
    if (base < 131072) { src = ldown; dst = ldb; off = base; }
    else               { src = lup;   dst = lub; off = base - 131072; }
    float4 v = *(const float4*)(src + off);
    bf16x4 bv = { f2b(v.x), f2b(v.y), f2b(v.z), f2b(v.w) };
    *(bf16x4*)(dst + off) = bv;
    return;
  }
  const int b = bid - 256;
  const int t = threadIdx.x;
  const int e = t >> 5, s = t & 31;
  const float* cls = x + (size_t)b * L_ * H_;
  const float* w   = rw + (size_t)e * H_;
  float p = 0.f;
#pragma unroll
  for (int c = s; c < 256; c += 32) {
    float4 xv = *(const float4*)(cls + 4 * c);
    float4 wv = *(const float4*)(w + 4 * c);
    p += xv.x * wv.x + xv.y * wv.y + xv.z * wv.z + xv.w * wv.w;
  }
#pragma unroll
  for (int off = 16; off; off >>= 1) p += __shfl_down(p, off, 32);
  __shared__ float logits[E_];
  if (s == 0) logits[e] = p;
  __syncthreads();
  if (t == 0) {
    float m0 = -1e30f; int i0 = 0;
    for (int j = 0; j < E_; ++j) if (logits[j] > m0) { m0 = logits[j]; i0 = j; }
    float m1 = -1e30f; int i1 = 0;
    for (int j = 0; j < E_; ++j) if (j != i0 && logits[j] > m1) { m1 = logits[j]; i1 = j; }
    float eb = expf(m1 - m0), inv = 1.f / (1.f + eb);
    gws[b * 4 + 0] = inv;
    gws[b * 4 + 1] = eb * inv;
    ((int*)gws)[b * 4 + 2] = i0;
    ((int*)gws)[b * 4 + 3] = i1;
  }
}

// ---------------- gates-only fallback (no-ws path) -------------------------
__global__ __launch_bounds__(256) void moe_gates_kernel(
    const float* __restrict__ x, const float* __restrict__ rw,
    float* __restrict__ gws)
{
  const int b = blockIdx.x;
  const int t = threadIdx.x;
  const int e = t >> 5, s = t & 31;
  const float* cls = x + (size_t)b * L_ * H_;
  const float* w   = rw + (size_t)e * H_;
  float p = 0.f;
#pragma unroll
  for (int c = s; c < 256; c += 32) {
    float4 xv = *(const float4*)(cls + 4 * c);
    float4 wv = *(const float4*)(w + 4 * c);
    p += xv.x * wv.x + xv.y * wv.y + xv.z * wv.z + xv.w * wv.w;
  }
#pragma unroll
  for (int off = 16; off; off >>= 1) p += __shfl_down(p, off, 32);
  __shared__ float logits[E_];
  if (s == 0) logits[e] = p;
  __syncthreads();
  if (t == 0) {
    float m0 = -1e30f; int i0 = 0;
    for (int j = 0; j < E_; ++j) if (logits[j] > m0) { m0 = logits[j]; i0 = j; }
    float m1 = -1e30f; int i1 = 0;
    for (int j = 0; j < E_; ++j) if (j != i0 && logits[j] > m1) { m1 = logits[j]; i1 = j; }
    float eb = expf(m1 - m0), inv = 1.f / (1.f + eb);
    gws[b * 4 + 0] = inv;
    gws[b * 4 + 1] = eb * inv;
    ((int*)gws)[b * 4 + 2] = i0;
    ((int*)gws)[b * 4 + 3] = i1;
  }
}

// ---------------- main: R14 verbatim (best proven: 41.8 us) ----------------
template<int BW>
__global__ __launch_bounds__(512, 4) void moe_main_kernel(
    const float* __restrict__ x,
    const __bf16* __restrict__ ldb, const __bf16* __restrict__ lub,
    const float* __restrict__ ldf, const float* __restrict__ luf,
    const float* __restrict__ gws, float* __restrict__ out)
{
  constexpr int XW = 1036;
  __shared__ __bf16 xs[16][XW];
  __shared__ f32x4  red[8][2][64];
  __shared__ __bf16 dg[16][40];

  const int t    = threadIdx.x;
  const int w    = t >> 6;
  const int lane = t & 63;
  const int gq   = lane >> 4;
  const int r16  = lane & 15;

  const int bid  = blockIdx.x;
  const int tile = (bid & 7) * 128 + (bid >> 3);
  const int b    = tile >> 5;
  const int l0   = (tile & 31) * 16;

  const float g0 = gws[b * 4 + 0];
  const float g1 = gws[b * 4 + 1];
  const int   e0 = ((const int*)gws)[b * 4 + 2];
  const int   e1 = ((const int*)gws)[b * 4 + 3];

  const float* xb = x + ((size_t)b * L_ + l0) * H_;

  {
    const int row = 2 * w + (lane >> 5);
    const int c0  = (lane & 31) * 4;
    const float* xrr = xb + (size_t)row * H_;
#pragma unroll
    for (int i = 0; i < 8; ++i) {
      float4 v = *(const float4*)(xrr + c0 + i * 128);
      bf16x4 bv = { f2b(v.x), f2b(v.y), f2b(v.z), f2b(v.w) };
      *(bf16x4*)&xs[row][c0 + i * 128] = bv;
    }
  }
  __syncthreads();

  f32x4 acc0 = {0.f, 0.f, 0.f, 0.f};
  f32x4 acc1 = {0.f, 0.f, 0.f, 0.f};
#pragma unroll
  for (int s = 0; s < 4; ++s) {
    const int kl = w * 128 + s * 32 + 4 * gq;
    bf16x4 xlo = *(const bf16x4*)&xs[r16][kl];
    bf16x4 xhi = *(const bf16x4*)&xs[r16][kl + 16];
    bf16x8 xq = { xlo[0], xlo[1], xlo[2], xlo[3],
                  xhi[0], xhi[1], xhi[2], xhi[3] };
    bf16x8 wf0, wf1;
    if constexpr (BW) {
      const __bf16* w0p = ldb + ((size_t)e0 * R_ + r16) * H_;
      const __bf16* w1p = ldb + ((size_t)e1 * R_ + r16) * H_;
      bf16x4 a0 = *(const bf16x4*)(w0p + kl);
      bf16x4 a1 = *(const bf16x4*)(w0p + kl + 16);
      bf16x4 b0 = *(const bf16x4*)(w1p + kl);
      bf16x4 b1 = *(const bf16x4*)(w1p + kl + 16);
      wf0 = bf16x8{ a0[0],a0[1],a0[2],a0[3], a1[0],a1[1],a1[2],a1[3] };
      wf1 = bf16x8{ b0[0],b0[1],b0[2],b0[3], b1[0],b1[1],b1[2],b1[3] };
    } else {
      const float* w0p = ldf + ((size_t)e0 * R_ + r16) * H_;
      const float* w1p = ldf + ((size_t)e1 * R_ + r16) * H_;
      float4 alo = *(const float4*)(w0p + kl);
      float4 ahi = *(const float4*)(w0p + kl + 16);
      float4 blo = *(const float4*)(w1p + kl);
      float4 bhi = *(const float4*)(w1p + kl + 16);
      wf0 = bf16x8{ f2b(alo.x), f2b(alo.y), f2b(alo.z), f2b(alo.w),
                    f2b(ahi.x), f2b(ahi.y), f2b(ahi.z), f2b(ahi.w) };
      wf1 = bf16x8{ f2b(blo.x), f2b(blo.y), f2b(blo.z), f2b(blo.w),
                    f2b(bhi.x), f2b(bhi.y), f2b(bhi.z), f2b(bhi.w) };
    }
    acc0 = MFMA(wf0, xq, acc0);
    acc1 = MFMA(wf1, xq, acc1);
  }
  red[w][0][lane] = acc0;
  red[w][1][lane] = acc1;
  __syncthreads();

  if (t < 128) {
    const int tl = t >> 6, slot = t & 63;
    f32x4 v = red[0][tl][slot];
#pragma unroll
    for (int q = 1; q < 8; ++q) v += red[q][tl][slot];
    const float g = tl ? g1 : g0;
    const int l  = slot & 15;
    const int p0 = tl * 16 + (slot >> 4) * 4;
#pragma unroll
    for (int j = 0; j < 4; ++j) dg[l][p0 + j] = f2b(v[j] * g);
  }
  __syncthreads();

  bf16x8 dfrag;
#pragma unroll
  for (int j = 0; j < 4; ++j) {
    dfrag[j]     = dg[r16][4 * gq + j];
    dfrag[4 + j] = dg[r16][16 + 4 * gq + j];
  }

#pragma unroll
  for (int nt = 0; nt < 8; ++nt) {
    const int h0 = w * 128 + nt * 16;
    const int ha = h0 + r16;
    bf16x8 uf;
    if constexpr (BW) {
      bf16x4 ulo = *(const bf16x4*)(lub + ((size_t)e0 * H_ + ha) * R_ + 4 * gq);
      bf16x4 uhi = *(const bf16x4*)(lub + ((size_t)e1 * H_ + ha) * R_ + 4 * gq);
      uf = bf16x8{ ulo[0],ulo[1],ulo[2],ulo[3], uhi[0],uhi[1],uhi[2],uhi[3] };
    } else {
      float4 ulo = *(const float4*)(luf + ((size_t)e0 * H_ + ha) * R_ + 4 * gq);
      float4 uhi = *(const float4*)(luf + ((size_t)e1 * H_ + ha) * R_ + 4 * gq);
      uf = bf16x8{ f2b(ulo.x), f2b(ulo.y), f2b(ulo.z), f2b(ulo.w),
                   f2b(uhi.x), f2b(uhi.y), f2b(uhi.z), f2b(uhi.w) };
    }
    bf16x4 rx = *(const bf16x4*)&xs[r16][h0 + 4 * gq];
    f32x4 acc = { (float)rx[0], (float)rx[1], (float)rx[2], (float)rx[3] };
    acc = MFMA(uf, dfrag, acc);
    bf16x4 ov = { f2b(acc[0]), f2b(acc[1]), f2b(acc[2]), f2b(acc[3]) };
    *(bf16x4*)&xs[r16][h0 + 4 * gq] = ov;
  }
  __syncthreads();

  {
    const int row = 2 * w + (lane >> 5);
    const int l32 = lane & 31;
    float* outrow = out + ((size_t)b * L_ + l0 + row) * H_;
#pragma unroll
    for (int it = 0; it < 8; ++it) {
      const int col = it * 128 + l32 * 4;
      bf16x4 v = *(const bf16x4*)&xs[row][col];
      float4 o = { (float)v[0], (float)v[1], (float)v[2], (float)v[3] };
      *(float4*)(outrow + col) = o;
    }
  }
}

extern "C" void kernel_launch(void* const* d_in, const int* in_sizes, int n_in,
                              void* d_out, int out_size, void* d_ws, size_t ws_size,
                              hipStream_t stream) {
  const float* x  = (const float*)d_in[0];
  const float* rw = (const float*)d_in[1];
  const float* ld = (const float*)d_in[2];
  const float* lu = (const float*)d_in[3];
  float* outp = (float*)d_out;

  float*  gws = (float*)d_ws;                         // 512 B
  __bf16* ldb = (__bf16*)((char*)d_ws + 1024);        // 256 KB
  __bf16* lub = ldb + 131072;                         // 256 KB

  // ---- ablations first; their output is overwritten by the real kernels ---
  hipLaunchKernelGGL(tile_copy_kernel, dim3(1024), dim3(512), 0, stream, x, outp);
  hipLaunchKernelGGL(shell_kernel,     dim3(1024), dim3(512), 0, stream, x, outp);

  if (ws_size >= 1024 + 2 * 131072 * sizeof(__bf16)) {
    hipLaunchKernelGGL(moe_prep_kernel, dim3(256 + B_), dim3(256), 0, stream,
                       x, rw, ld, lu, ldb, lub, gws);
    hipLaunchKernelGGL(moe_main_kernel<1>, dim3(1024), dim3(512), 0, stream,
                       x, ldb, lub, nullptr, nullptr, gws, outp);
  } else {
    hipLaunchKernelGGL(moe_gates_kernel, dim3(B_), dim3(256), 0, stream,
                       x, rw, gws);
    hipLaunchKernelGGL(moe_main_kernel<0>, dim3(1024), dim3(512), 0, stream,
                       x, nullptr, nullptr, ld, lu, gws, outp);
  }
}

// Round 19
// 47.087 us; speedup vs baseline: 1.6929x; 1.6929x over previous
//
#include <hip/hip_runtime.h>
#include <hip/hip_bf16.h>

#define B_ 32
#define L_ 512
#define H_ 1024
#define E_ 8
#define R_ 16

typedef float f32x4 __attribute__((ext_vector_type(4)));
typedef __bf16 bf16x8 __attribute__((ext_vector_type(8)));
typedef __bf16 bf16x4 __attribute__((ext_vector_type(4)));

static __device__ __forceinline__ __bf16 f2b(float f) { return (__bf16)f; }

static __device__ __forceinline__ f32x4 MFMA(bf16x8 a, bf16x8 b, f32x4 c) {
  return __builtin_amdgcn_mfma_f32_16x16x32_bf16(a, b, c, 0, 0, 0);
}

// ---------------- prep: f32 weights -> bf16 in ws; + gates -----------------
__global__ __launch_bounds__(256) void moe_prep_kernel(
    const float* __restrict__ x, const float* __restrict__ rw,
    const float* __restrict__ ldown, const float* __restrict__ lup,
    __bf16* __restrict__ ldb, __bf16* __restrict__ lub,
    float* __restrict__ gws)
{
  const int bid = blockIdx.x;
  if (bid < 256) {
    const int base = bid * 1024 + threadIdx.x * 4;
    const float* src; __bf16* dst; int off;
    if (base < 131072) { src = ldown; dst = ldb; off = base; }
    else               { src = lup;   dst = lub; off = base - 131072; }
    float4 v = *(const float4*)(src + off);
    bf16x4 bv = { f2b(v.x), f2b(v.y), f2b(v.z), f2b(v.w) };
    *(bf16x4*)(dst + off) = bv;
    return;
  }
  const int b = bid - 256;
  const int t = threadIdx.x;
  const int e = t >> 5, s = t & 31;
  const float* cls = x + (size_t)b * L_ * H_;
  const float* w   = rw + (size_t)e * H_;
  float p = 0.f;
#pragma unroll
  for (int c = s; c < 256; c += 32) {
    float4 xv = *(const float4*)(cls + 4 * c);
    float4 wv = *(const float4*)(w + 4 * c);
    p += xv.x * wv.x + xv.y * wv.y + xv.z * wv.z + xv.w * wv.w;
  }
#pragma unroll
  for (int off = 16; off; off >>= 1) p += __shfl_down(p, off, 32);
  __shared__ float logits[E_];
  if (s == 0) logits[e] = p;
  __syncthreads();
  if (t == 0) {
    float m0 = -1e30f; int i0 = 0;
    for (int j = 0; j < E_; ++j) if (logits[j] > m0) { m0 = logits[j]; i0 = j; }
    float m1 = -1e30f; int i1 = 0;
    for (int j = 0; j < E_; ++j) if (j != i0 && logits[j] > m1) { m1 = logits[j]; i1 = j; }
    float eb = expf(m1 - m0), inv = 1.f / (1.f + eb);
    gws[b * 4 + 0] = inv;
    gws[b * 4 + 1] = eb * inv;
    ((int*)gws)[b * 4 + 2] = i0;
    ((int*)gws)[b * 4 + 3] = i1;
  }
}

// ---------------- gates-only fallback (no-ws path) -------------------------
__global__ __launch_bounds__(256) void moe_gates_kernel(
    const float* __restrict__ x, const float* __restrict__ rw,
    float* __restrict__ gws)
{
  const int b = blockIdx.x;
  const int t = threadIdx.x;
  const int e = t >> 5, s = t & 31;
  const float* cls = x + (size_t)b * L_ * H_;
  const float* w   = rw + (size_t)e * H_;
  float p = 0.f;
#pragma unroll
  for (int c = s; c < 256; c += 32) {
    float4 xv = *(const float4*)(cls + 4 * c);
    float4 wv = *(const float4*)(w + 4 * c);
    p += xv.x * wv.x + xv.y * wv.y + xv.z * wv.z + xv.w * wv.w;
  }
#pragma unroll
  for (int off = 16; off; off >>= 1) p += __shfl_down(p, off, 32);
  __shared__ float logits[E_];
  if (s == 0) logits[e] = p;
  __syncthreads();
  if (t == 0) {
    float m0 = -1e30f; int i0 = 0;
    for (int j = 0; j < E_; ++j) if (logits[j] > m0) { m0 = logits[j]; i0 = j; }
    float m1 = -1e30f; int i1 = 0;
    for (int j = 0; j < E_; ++j) if (j != i0 && logits[j] > m1) { m1 = logits[j]; i1 = j; }
    float eb = expf(m1 - m0), inv = 1.f / (1.f + eb);
    gws[b * 4 + 0] = inv;
    gws[b * 4 + 1] = eb * inv;
    ((int*)gws)[b * 4 + 2] = i0;
    ((int*)gws)[b * 4 + 3] = i1;
  }
}

// ---------------- main: 2 tiles/block, reg-resident weights, prefetch ------
// Both tiles share b -> Wd and U live in registers across both tiles, so
// phases A/B issue NO global loads. Tile1's x rows are prefetched into
// registers BEFORE A(t0) and consumed after pack(t0): with raw s_barrier
// (no vmcnt drain) and no newer-load uses in between, the 8 loads stay in
// flight under A(t0)+pack (in-order vmcnt respected). Epilogue(t0) stores
// are co-scheduled with A(t1). Phase math is R14/R15-verbatim.
template<int BW>
__global__ __launch_bounds__(512, 4) void moe_main_kernel(
    const float* __restrict__ x,
    const __bf16* __restrict__ ldb, const __bf16* __restrict__ lub,
    const float* __restrict__ ldf, const float* __restrict__ luf,
    const float* __restrict__ gws, float* __restrict__ out)
{
  constexpr int XW = 1036;                  // 518 dw/row, %32==6 (bank-spread)
  __shared__ __bf16 xs0[16][XW];            // 33,152 B tile0
  __shared__ __bf16 xs1[16][XW];            // 33,152 B tile1
  __shared__ float  dgf[2][16][16];         //  2,048 B atomic K-reduce
  __shared__ __bf16 dg[16][40];             //  1,280 B gated bf16 D

  const int t    = threadIdx.x;
  const int w    = t >> 6;
  const int lane = t & 63;
  const int gq   = lane >> 4;
  const int r16  = lane & 15;

  const int bid  = blockIdx.x;              // 512 blocks
  const int swz  = (bid & 7) * 64 + (bid >> 3);   // XCD swizzle (bijective)
  const int tl0  = swz * 2;
  const int b    = tl0 >> 5;
  const int l00  = (tl0 & 31) * 16;
  const int l01  = l00 + 16;

  const float g0 = gws[b * 4 + 0];
  const float g1 = gws[b * 4 + 1];
  const int   e0 = ((const int*)gws)[b * 4 + 2];
  const int   e1 = ((const int*)gws)[b * 4 + 3];

  ((float*)dgf)[t] = 0.f;

  // ---- Wd -> registers (8 x bf16x8 = 32 VGPR), reused by both tiles -------
  bf16x8 wd0[4], wd1[4];
#pragma unroll
  for (int s = 0; s < 4; ++s) {
    const int kl = w * 128 + s * 32 + 4 * gq;
    if constexpr (BW) {
      const __bf16* w0p = ldb + ((size_t)e0 * R_ + r16) * H_;
      const __bf16* w1p = ldb + ((size_t)e1 * R_ + r16) * H_;
      bf16x4 a0 = *(const bf16x4*)(w0p + kl);
      bf16x4 a1 = *(const bf16x4*)(w0p + kl + 16);
      bf16x4 b0 = *(const bf16x4*)(w1p + kl);
      bf16x4 b1 = *(const bf16x4*)(w1p + kl + 16);
      wd0[s] = bf16x8{ a0[0],a0[1],a0[2],a0[3], a1[0],a1[1],a1[2],a1[3] };
      wd1[s] = bf16x8{ b0[0],b0[1],b0[2],b0[3], b1[0],b1[1],b1[2],b1[3] };
    } else {
      const float* w0p = ldf + ((size_t)e0 * R_ + r16) * H_;
      const float* w1p = ldf + ((size_t)e1 * R_ + r16) * H_;
      float4 alo = *(const float4*)(w0p + kl);
      float4 ahi = *(const float4*)(w0p + kl + 16);
      float4 blo = *(const float4*)(w1p + kl);
      float4 bhi = *(const float4*)(w1p + kl + 16);
      wd0[s] = bf16x8{ f2b(alo.x), f2b(alo.y), f2b(alo.z), f2b(alo.w),
                       f2b(ahi.x), f2b(ahi.y), f2b(ahi.z), f2b(ahi.w) };
      wd1[s] = bf16x8{ f2b(blo.x), f2b(blo.y), f2b(blo.z), f2b(blo.w),
                       f2b(bhi.x), f2b(bhi.y), f2b(bhi.z), f2b(bhi.w) };
    }
  }

  const int srow = 2 * w + (lane >> 5);
  const int sc0  = (lane & 31) * 4;

  // ---- stage tile0 --------------------------------------------------------
  {
    const float* xrr = x + ((size_t)b * L_ + l00 + srow) * H_;
#pragma unroll
    for (int i = 0; i < 8; ++i) {
      float4 v = *(const float4*)(xrr + sc0 + i * 128);
      bf16x4 bv = { f2b(v.x), f2b(v.y), f2b(v.z), f2b(v.w) };
      *(bf16x4*)&xs0[srow][sc0 + i * 128] = bv;
    }
  }
  __syncthreads();                          // stage0 + dgf zero visible

  // ---- issue tile1 prefetch (8 float4 = 32 VGPR, consumed 2 barriers later)
  const float* xr1 = x + ((size_t)b * L_ + l01 + srow) * H_;
  float4 p0 = *(const float4*)(xr1 + sc0 + 0 * 128);
  float4 p1 = *(const float4*)(xr1 + sc0 + 1 * 128);
  float4 p2 = *(const float4*)(xr1 + sc0 + 2 * 128);
  float4 p3 = *(const float4*)(xr1 + sc0 + 3 * 128);
  float4 p4 = *(const float4*)(xr1 + sc0 + 4 * 128);
  float4 p5 = *(const float4*)(xr1 + sc0 + 5 * 128);
  float4 p6 = *(const float4*)(xr1 + sc0 + 6 * 128);
  float4 p7 = *(const float4*)(xr1 + sc0 + 7 * 128);

  auto BARRIER = []() {
    asm volatile("s_waitcnt lgkmcnt(0)" ::: "memory");
    __builtin_amdgcn_s_barrier();
  };

  auto PHASE_A = [&](const __bf16 (*xsb)[XW]) {
    f32x4 a0v = {0.f, 0.f, 0.f, 0.f};
    f32x4 a1v = {0.f, 0.f, 0.f, 0.f};
#pragma unroll
    for (int s = 0; s < 4; ++s) {
      const int kl = w * 128 + s * 32 + 4 * gq;
      bf16x4 xlo = *(const bf16x4*)&xsb[r16][kl];
      bf16x4 xhi = *(const bf16x4*)&xsb[r16][kl + 16];
      bf16x8 xq = { xlo[0], xlo[1], xlo[2], xlo[3],
                    xhi[0], xhi[1], xhi[2], xhi[3] };
      a0v = MFMA(wd0[s], xq, a0v);
      a1v = MFMA(wd1[s], xq, a1v);
    }
#pragma unroll
    for (int j = 0; j < 4; ++j) {
      atomicAdd(&dgf[0][r16][4 * gq + j], a0v[j]);
      atomicAdd(&dgf[1][r16][4 * gq + j], a1v[j]);
    }
  };

  auto PACK = [&]() {
    if (t < 128) {
      const int e = t >> 6, slot = t & 63;
      const int l  = slot & 15;
      const int pp = (slot >> 4) * 4;
      const float g = e ? g1 : g0;
#pragma unroll
      for (int j = 0; j < 4; ++j) {
        dg[l][e * 16 + pp + j] = f2b(dgf[e][l][pp + j] * g);
        dgf[e][l][pp + j] = 0.f;
      }
    }
  };

  bf16x8 ufr[8];                            // U regs, loaded in B(t0), reused
  auto LOAD_U = [&]() {
#pragma unroll
    for (int nt = 0; nt < 8; ++nt) {
      const int ha = w * 128 + nt * 16 + r16;
      if constexpr (BW) {
        bf16x4 ulo = *(const bf16x4*)(lub + ((size_t)e0 * H_ + ha) * R_ + 4 * gq);
        bf16x4 uhi = *(const bf16x4*)(lub + ((size_t)e1 * H_ + ha) * R_ + 4 * gq);
        ufr[nt] = bf16x8{ ulo[0],ulo[1],ulo[2],ulo[3],
                          uhi[0],uhi[1],uhi[2],uhi[3] };
      } else {
        float4 ulo = *(const float4*)(luf + ((size_t)e0 * H_ + ha) * R_ + 4 * gq);
        float4 uhi = *(const float4*)(luf + ((size_t)e1 * H_ + ha) * R_ + 4 * gq);
        ufr[nt] = bf16x8{ f2b(ulo.x), f2b(ulo.y), f2b(ulo.z), f2b(ulo.w),
                          f2b(uhi.x), f2b(uhi.y), f2b(uhi.z), f2b(uhi.w) };
      }
    }
  };

  auto PHASE_B = [&](__bf16 (*xsb)[XW]) {
    bf16x8 dfrag;
#pragma unroll
    for (int j = 0; j < 4; ++j) {
      dfrag[j]     = dg[r16][4 * gq + j];
      dfrag[4 + j] = dg[r16][16 + 4 * gq + j];
    }
#pragma unroll
    for (int nt = 0; nt < 8; ++nt) {
      const int h0 = w * 128 + nt * 16;
      bf16x4 rx = *(const bf16x4*)&xsb[r16][h0 + 4 * gq];
      f32x4 acc = { (float)rx[0], (float)rx[1], (float)rx[2], (float)rx[3] };
      acc = MFMA(ufr[nt], dfrag, acc);
      bf16x4 ov = { f2b(acc[0]), f2b(acc[1]), f2b(acc[2]), f2b(acc[3]) };
      *(bf16x4*)&xsb[r16][h0 + 4 * gq] = ov;
    }
  };

  auto EPILOGUE = [&](const __bf16 (*xsb)[XW], int l0) {
    float* outrow = out + ((size_t)b * L_ + l0 + srow) * H_;
#pragma unroll
    for (int it = 0; it < 8; ++it) {
      const int col = it * 128 + (lane & 31) * 4;
      bf16x4 v = *(const bf16x4*)&xsb[srow][col];
      float4 o = { (float)v[0], (float)v[1], (float)v[2], (float)v[3] };
      *(float4*)(outrow + col) = o;
    }
  };

  // ==== tile0 ==============================================================
  PHASE_A(xs0);                             // no global loads; prefetch in flight
  BARRIER();
  PACK();
  BARRIER();

  // consume prefetch -> xs1 (first use of p*: compiler inserts vmcnt wait)
  {
    bf16x4 s0 = { f2b(p0.x), f2b(p0.y), f2b(p0.z), f2b(p0.w) };
    bf16x4 s1 = { f2b(p1.x), f2b(p1.y), f2b(p1.z), f2b(p1.w) };
    bf16x4 s2 = { f2b(p2.x), f2b(p2.y), f2b(p2.z), f2b(p2.w) };
    bf16x4 s3 = { f2b(p3.x), f2b(p3.y), f2b(p3.z), f2b(p3.w) };
    bf16x4 s4 = { f2b(p4.x), f2b(p4.y), f2b(p4.z), f2b(p4.w) };
    bf16x4 s5 = { f2b(p5.x), f2b(p5.y), f2b(p5.z), f2b(p5.w) };
    bf16x4 s6 = { f2b(p6.x), f2b(p6.y), f2b(p6.z), f2b(p6.w) };
    bf16x4 s7 = { f2b(p7.x), f2b(p7.y), f2b(p7.z), f2b(p7.w) };
    *(bf16x4*)&xs1[srow][sc0 + 0 * 128] = s0;
    *(bf16x4*)&xs1[srow][sc0 + 1 * 128] = s1;
    *(bf16x4*)&xs1[srow][sc0 + 2 * 128] = s2;
    *(bf16x4*)&xs1[srow][sc0 + 3 * 128] = s3;
    *(bf16x4*)&xs1[srow][sc0 + 4 * 128] = s4;
    *(bf16x4*)&xs1[srow][sc0 + 5 * 128] = s5;
    *(bf16x4*)&xs1[srow][sc0 + 6 * 128] = s6;
    *(bf16x4*)&xs1[srow][sc0 + 7 * 128] = s7;
  }
  LOAD_U();                                 // issued after prefetch drained
  PHASE_B(xs0);                             // in-place bf16 results
  BARRIER();                                // xs1 + xs0-results visible

  // ==== epilogue(t0) co-scheduled with A(t1): stores drain under compute ===
  EPILOGUE(xs0, l00);
  PHASE_A(xs1);
  BARRIER();
  PACK();
  BARRIER();
  PHASE_B(xs1);                             // U from registers, no loads
  BARRIER();
  EPILOGUE(xs1, l01);
}

extern "C" void kernel_launch(void* const* d_in, const int* in_sizes, int n_in,
                              void* d_out, int out_size, void* d_ws, size_t ws_size,
                              hipStream_t stream) {
  const float* x  = (const float*)d_in[0];
  const float* rw = (const float*)d_in[1];
  const float* ld = (const float*)d_in[2];
  const float* lu = (const float*)d_in[3];
  float* outp = (float*)d_out;

  float*  gws = (float*)d_ws;                         // 512 B
  __bf16* ldb = (__bf16*)((char*)d_ws + 1024);        // 256 KB
  __bf16* lub = ldb + 131072;                         // 256 KB

  if (ws_size >= 1024 + 2 * 131072 * sizeof(__bf16)) {
    hipLaunchKernelGGL(moe_prep_kernel, dim3(256 + B_), dim3(256), 0, stream,
                       x, rw, ld, lu, ldb, lub, gws);
    hipLaunchKernelGGL(moe_main_kernel<1>, dim3(512), dim3(512), 0, stream,
                       x, ldb, lub, nullptr, nullptr, gws, outp);
  } else {
    hipLaunchKernelGGL(moe_gates_kernel, dim3(B_), dim3(256), 0, stream,
                       x, rw, gws);
    hipLaunchKernelGGL(moe_main_kernel<0>, dim3(512), dim3(512), 0, stream,
                       x, nullptr, nullptr, ld, lu, gws, outp);
  }
}